// Round 2
// baseline (748.111 us; speedup 1.0000x reference)
//
#include <hip/hip_runtime.h>
#include <stdint.h>

#define BDIM   256
#define NROWS  32
#define CDIM   1024
#define NSTEPS (NROWS - 1)
#define BATCH  512

// One workgroup per batch. Entire 31-step merge chain runs in-block.
// Distance matrix (fp64) kept in LDS by logical position, ping-pong remapped
// each step. Row data: original rows read from d_in (fp32), merged rows
// stored fp32 in d_ws. Logical row -> storage slot via idx[] indirection.
__global__ __launch_bounds__(BDIM)
void merge_tree_kernel(const float* __restrict__ xin,  // B*32*1024 fp32
                       const float* __restrict__ wz,   // 6 fp32 (1,2,3)
                       const float* __restrict__ bz,   // 1 fp32
                       float* __restrict__ out,        // B*1024 fp32
                       float* __restrict__ ws)         // B*31*1024 fp32
{
    const int b    = blockIdx.x;
    const int tid  = threadIdx.x;
    const int lane = tid & 63;
    const int wv   = tid >> 6;

    const float* xb  = xin + (size_t)b * NROWS * CDIM;
    float*       wsb = ws  + (size_t)b * NSTEPS * CDIM;

    __shared__ double Dm[2][NROWS][NROWS + 1]; // d2 by logical position (symmetric)
    __shared__ double sqv[2][NROWS];           // squared norms by logical position
    __shared__ int    idxv[2][NROWS];          // logical position -> storage slot
    __shared__ int    srcmap[NROWS];           // new logical -> old logical (this step)
    __shared__ float  mrow[CDIM];              // staging / merged row (fp32)
    __shared__ double redv[BDIM];
    __shared__ int    redp[BDIM];
    __shared__ int    sAB[2];

    // conv weights: conv_w[0][i][k] at flat i*3+k
    float W0[3], W1[3];
    #pragma unroll
    for (int k = 0; k < 3; k++) { W0[k] = wz[k]; W1[k] = wz[3 + k]; }
    const float CB = bz[0];

    // element of storage slot s (s<32: original input; s>=32: merged row in ws)
    auto loadElem = [&](int slot, int c) -> float {
        return (slot < NROWS) ? xb[slot * CDIM + c]
                              : wsb[(slot - NROWS) * CDIM + c];
    };

    // one wave: dot(mrow, row[slot]) in fp64; valid on lane 0
    auto waveDot = [&](int slot) -> double {
        double acc = 0.0;
        const float* p = (slot < NROWS) ? (xb + slot * CDIM)
                                        : (wsb + (slot - NROWS) * CDIM);
        #pragma unroll 4
        for (int c = lane; c < CDIM; c += 64)
            acc += (double)mrow[c] * (double)p[c];
        #pragma unroll
        for (int off = 32; off > 0; off >>= 1)
            acc += __shfl_down(acc, off, 64);
        return acc;
    };

    // ---------- init: squared norms ----------
    for (int r = wv; r < NROWS; r += 4) {
        double acc = 0.0;
        const float* p = xb + r * CDIM;
        for (int c = lane; c < CDIM; c += 64) {
            double v = (double)p[c];
            acc += v * v;
        }
        #pragma unroll
        for (int off = 32; off > 0; off >>= 1)
            acc += __shfl_down(acc, off, 64);
        if (lane == 0) sqv[0][r] = acc;
    }
    if (tid < NROWS) idxv[0][tid] = tid;
    __syncthreads();

    // ---------- init: pairwise d2 matrix ----------
    for (int i = 0; i < NROWS - 1; i++) {
        for (int c = tid; c < CDIM; c += BDIM) mrow[c] = xb[i * CDIM + c];
        __syncthreads();
        for (int j = i + 1 + wv; j < NROWS; j += 4) {
            double d = waveDot(j);
            if (lane == 0) {
                double v = sqv[0][i] + sqv[0][j] - 2.0 * d;
                Dm[0][i][j] = v;
                Dm[0][j][i] = v;
            }
        }
        __syncthreads();
    }

    // ---------- main merge loop ----------
    int p = 0;
    for (int step = 0; step < NSTEPS; step++) {
        const int n = NROWS - step;
        double (*D)[NROWS + 1] = Dm[p];
        double (*E)[NROWS + 1] = Dm[p ^ 1];
        double *sq  = sqv[p],  *nsq  = sqv[p ^ 1];
        int    *idx = idxv[p], *nidx = idxv[p ^ 1];

        // --- argmin over pairs (i<j), reference order: fp32 dist, then flat idx ---
        double bv = 1e300;
        int    bp = 0x7fffffff;
        for (int flat = tid; flat < n * n; flat += BDIM) {
            int i = flat / n, j = flat - i * n;
            if (j > i) {
                double d2 = D[i][j];
                float  df = (float)(d2 > 0.0 ? sqrt(d2) : 0.0);
                double key = (double)df;
                if (key < bv || (key == bv && flat < bp)) { bv = key; bp = flat; }
            }
        }
        redv[tid] = bv; redp[tid] = bp;
        __syncthreads();
        for (int s = BDIM / 2; s > 0; s >>= 1) {
            if (tid < s) {
                double ov = redv[tid + s]; int op = redp[tid + s];
                if (ov < redv[tid] || (ov == redv[tid] && op < redp[tid])) {
                    redv[tid] = ov; redp[tid] = op;
                }
            }
            __syncthreads();
        }
        if (tid == 0) { sAB[0] = redp[0] / n; sAB[1] = redp[0] % n; }
        __syncthreads();
        const int a  = sAB[0];
        const int bb = sAB[1];
        const int sa = idx[a], sb = idx[bb];
        const int mslot = NROWS + step;

        // --- conv merge: out[h] = relu(b + sum_k W0[k]*xa[h+k-1] + W1[k]*xb[h+k-1]) ---
        double sqpart = 0.0;
        for (int h = tid; h < CDIM; h += BDIM) {
            double acc = (double)CB;
            #pragma unroll
            for (int k = 0; k < 3; k++) {
                int c = h + k - 1;
                if (c >= 0 && c < CDIM) {
                    acc += (double)W0[k] * (double)loadElem(sa, c);
                    acc += (double)W1[k] * (double)loadElem(sb, c);
                }
            }
            float m = (acc > 0.0) ? (float)acc : 0.0f;
            mrow[h] = m;
            wsb[(mslot - NROWS) * CDIM + h] = m;
            sqpart += (double)m * (double)m;
        }
        redv[tid] = sqpart;
        __syncthreads();
        for (int s = BDIM / 2; s > 0; s >>= 1) {
            if (tid < s) redv[tid] += redv[tid + s];
            __syncthreads();
        }
        const double sqm = redv[0];

        // --- build new logical order ---
        // new[0] = merged; new[k-1] = old[k] for k=2..n-1, except:
        //   pos bb <- old row 1; pos a <- old row 0 (only reachable when a>=2).
        // When a==1 old row 0 is dropped (reference quirk).
        const int m1 = n - 1;
        if (tid < m1) {
            if (tid == 0) {
                nidx[0] = mslot; nsq[0] = sqm; srcmap[0] = -1;
            } else {
                int k = tid + 1;
                int src = (k == bb) ? 1 : ((k == a) ? 0 : k);
                nidx[tid] = idx[src]; nsq[tid] = sq[src]; srcmap[tid] = src;
            }
        }
        __syncthreads();

        // --- remap surviving distances (positions >=1) ---
        for (int fl = tid; fl < m1 * m1; fl += BDIM) {
            int l1 = fl / m1, l2 = fl - l1 * m1;
            if (l1 >= 1 && l2 >= 1 && l1 != l2)
                E[l1][l2] = D[srcmap[l1]][srcmap[l2]];
        }

        // --- distances merged-row vs survivors (fills row/col 0 of E) ---
        for (int l = 1 + wv; l < m1; l += 4) {
            double d = waveDot(nidx[l]);
            if (lane == 0) {
                double v = sqm + nsq[l] - 2.0 * d;
                E[0][l] = v;
                E[l][0] = v;
            }
        }
        __syncthreads();
        p ^= 1;
    }

    // final merged row (step 30) is in mrow; each thread wrote mrow[c] for c==tid mod BDIM
    for (int c = tid; c < CDIM; c += BDIM)
        out[(size_t)b * CDIM + c] = mrow[c];
}

extern "C" void kernel_launch(void* const* d_in, const int* in_sizes, int n_in,
                              void* d_out, int out_size, void* d_ws, size_t ws_size,
                              hipStream_t stream) {
    const float* x  = (const float*)d_in[0]; // fp32 (512,32,1024)
    const float* w  = (const float*)d_in[1]; // fp32 (1,2,3)
    const float* cb = (const float*)d_in[2]; // fp32 (1,)
    float* out = (float*)d_out;              // fp32 (512,1024)
    float* ws  = (float*)d_ws;               // 512*31*1024 fp32 merged rows

    hipLaunchKernelGGL(merge_tree_kernel, dim3(BATCH), dim3(BDIM), 0, stream,
                       x, w, cb, out, ws);
}

// Round 3
// 613.747 us; speedup vs baseline: 1.2189x; 1.2189x over previous
//
#include <hip/hip_runtime.h>
#include <stdint.h>

#define BDIM   1024
#define NROWS  32
#define CDIM   1024
#define NSTEPS (NROWS - 1)
#define BATCH  512

// One 1024-thread workgroup per batch; whole 31-step merge chain in-block.
// Distance matrix (fp64) in LDS, ping-pong remapped by logical position.
// Row data: originals read from d_in, merged rows stored fp32 in d_ws.
// block=1024: conv/argmin/remap are single-iteration; each 32-lane group
// computes one merged-vs-survivor dot (all rows in parallel).
__global__ __launch_bounds__(BDIM, 8)
void merge_tree_kernel(const float* __restrict__ xin,  // B*32*1024 fp32
                       const float* __restrict__ wz,   // 6 fp32 (1,2,3)
                       const float* __restrict__ bz,   // 1 fp32
                       float* __restrict__ out,        // B*1024 fp32
                       float* __restrict__ ws)         // B*31*1024 fp32
{
    const int b    = blockIdx.x;
    const int tid  = threadIdx.x;
    const int lane = tid & 63;
    const int wid  = tid >> 6;   // 0..15
    const int g32  = tid >> 5;   // 0..31 (32-thread group id)
    const int j32  = tid & 31;   // lane within group

    const float* xb  = xin + (size_t)b * NROWS * CDIM;
    float*       wsb = ws  + (size_t)b * NSTEPS * CDIM;

    __shared__ double Dm[2][NROWS][NROWS + 1];
    __shared__ double sqv[2][NROWS];
    __shared__ int    idxv[2][NROWS];
    __shared__ int    srcmap[NROWS];
    __shared__ float  mrow[CDIM];
    __shared__ double wredv[16];
    __shared__ int    wredp[16];
    __shared__ double wsum[16];
    __shared__ double sqmS;
    __shared__ int    sAB[2];

    float W0[3], W1[3];
    #pragma unroll
    for (int k = 0; k < 3; k++) { W0[k] = wz[k]; W1[k] = wz[3 + k]; }
    const float CB = bz[0];

    auto rowPtr = [&](int slot) -> const float* {
        return (slot < NROWS) ? (xb + slot * CDIM)
                              : (wsb + (slot - NROWS) * CDIM);
    };
    // sum within 32-thread group; valid at group lane 0
    auto grpSum = [&](double v) -> double {
        #pragma unroll
        for (int off = 16; off > 0; off >>= 1) v += __shfl_down(v, off, 64);
        return v;
    };

    // ---------- init: squared norms (group g -> row g) ----------
    {
        const float* p = xb + g32 * CDIM;
        double acc = 0.0;
        #pragma unroll 4
        for (int k = j32; k < CDIM; k += 32) { double v = (double)p[k]; acc += v * v; }
        acc = grpSum(acc);
        if (j32 == 0) sqv[0][g32] = acc;
        if (tid < NROWS) idxv[0][tid] = tid;
    }
    __syncthreads();

    // ---------- init: pairwise d2, balanced over groups ----------
    // pairs enumerated by diagonal d=1..31 (32-d pairs each), v = linear pair idx
    for (int v = g32; v < (NROWS * (NROWS - 1)) / 2; v += 32) {
        int r = v, d = 1;
        while (r >= NROWS - d) { r -= NROWS - d; d++; }
        int i = r, j = i + d;
        const float* pi = xb + i * CDIM;
        const float* pj = xb + j * CDIM;
        double acc = 0.0;
        #pragma unroll 4
        for (int k = j32; k < CDIM; k += 32) acc += (double)pi[k] * (double)pj[k];
        acc = grpSum(acc);
        if (j32 == 0) {
            double dv = sqv[0][i] + sqv[0][j] - 2.0 * acc;
            Dm[0][i][j] = dv;
            Dm[0][j][i] = dv;
        }
    }
    __syncthreads();

    // ---------- main merge loop ----------
    int p = 0;
    float lastm = 0.0f;
    for (int step = 0; step < NSTEPS; step++) {
        const int n = NROWS - step;
        double (*D)[NROWS + 1] = Dm[p];
        double (*E)[NROWS + 1] = Dm[p ^ 1];
        double *sq  = sqv[p],  *nsq  = sqv[p ^ 1];
        int    *idx = idxv[p], *nidx = idxv[p ^ 1];

        // --- argmin over pairs (i<j): key = fp32 dist, tie -> smaller flat ---
        double bv = 1e300;
        int    bp = 0x7fffffff;
        if (tid < n * n) {
            int i = tid / n, j = tid - i * n;
            if (j > i) {
                double d2 = D[i][j];
                float  df = (float)((d2 > 0.0) ? sqrt(d2) : 0.0);
                bv = (double)df; bp = tid;
            }
        }
        #pragma unroll
        for (int off = 32; off > 0; off >>= 1) {
            double ov = __shfl_down(bv, off); int op = __shfl_down(bp, off);
            if (ov < bv || (ov == bv && op < bp)) { bv = ov; bp = op; }
        }
        if (lane == 0) { wredv[wid] = bv; wredp[wid] = bp; }
        __syncthreads();                                   // B1
        if (wid == 0) {
            double v = (lane < 16) ? wredv[lane] : 1e300;
            int    q = (lane < 16) ? wredp[lane] : 0x7fffffff;
            #pragma unroll
            for (int off = 8; off > 0; off >>= 1) {
                double ov = __shfl_down(v, off); int oq = __shfl_down(q, off);
                if (ov < v || (ov == v && oq < q)) { v = ov; q = oq; }
            }
            if (lane == 0) { sAB[0] = q / n; sAB[1] = q % n; }
        }
        __syncthreads();                                   // B2

        const int a  = sAB[0];
        const int bb = sAB[1];
        const int sa = idx[a], sb = idx[bb];
        const int mslot = NROWS + step;
        const float* pa = rowPtr(sa);
        const float* pb = rowPtr(sb);

        // --- conv merge (thread tid == output position h) + wave partial sq ---
        {
            const int h = tid;
            double acc = (double)CB;
            if (h > 0)
                acc += (double)W0[0] * (double)pa[h - 1] + (double)W1[0] * (double)pb[h - 1];
            acc     += (double)W0[1] * (double)pa[h]     + (double)W1[1] * (double)pb[h];
            if (h < CDIM - 1)
                acc += (double)W0[2] * (double)pa[h + 1] + (double)W1[2] * (double)pb[h + 1];
            float m = (acc > 0.0) ? (float)acc : 0.0f;
            lastm = m;
            mrow[h] = m;
            wsb[(mslot - NROWS) * CDIM + h] = m;
            double s = (double)m * (double)m;
            #pragma unroll
            for (int off = 32; off > 0; off >>= 1) s += __shfl_down(s, off);
            if (lane == 0) wsum[wid] = s;
        }
        __syncthreads();                                   // B3

        // --- cross-wave sq sum; build new logical order ---
        // new[0]=merged; new[k-1]=old[k], overrides: pos bb<-old1, pos a<-old0
        // (a==1: old row 0 dropped — reference quirk)
        const int m1 = n - 1;
        if (wid == 0) {
            double s = (lane < 16) ? wsum[lane] : 0.0;
            #pragma unroll
            for (int off = 8; off > 0; off >>= 1) s += __shfl_down(s, off);
            if (lane == 0) { sqmS = s; nsq[0] = s; nidx[0] = mslot; srcmap[0] = -1; }
        }
        if (tid >= 1 && tid < m1) {
            int k = tid + 1;
            int src = (k == bb) ? 1 : ((k == a) ? 0 : k);
            nidx[tid] = idx[src]; nsq[tid] = sq[src]; srcmap[tid] = src;
        }
        __syncthreads();                                   // B4

        // --- remap surviving distances (single iteration) ---
        if (tid < m1 * m1) {
            int l1 = tid / m1, l2 = tid - l1 * m1;
            if (l1 >= 1 && l2 >= 1 && l1 != l2)
                E[l1][l2] = D[srcmap[l1]][srcmap[l2]];
        }
        // --- dots merged-vs-survivor: group g handles logical row l=1+g ---
        {
            const int l = 1 + g32;
            if (l < m1) {
                const float* pr = rowPtr(nidx[l]);
                double acc = 0.0;
                #pragma unroll 4
                for (int k = j32; k < CDIM; k += 32)
                    acc += (double)mrow[k] * (double)pr[k];
                acc = grpSum(acc);
                if (j32 == 0) {
                    double v = sqmS + nsq[l] - 2.0 * acc;
                    E[0][l] = v;
                    E[l][0] = v;
                }
            }
        }
        __syncthreads();                                   // B5
        p ^= 1;
    }

    out[(size_t)b * CDIM + tid] = lastm;
}

extern "C" void kernel_launch(void* const* d_in, const int* in_sizes, int n_in,
                              void* d_out, int out_size, void* d_ws, size_t ws_size,
                              hipStream_t stream) {
    const float* x  = (const float*)d_in[0]; // fp32 (512,32,1024)
    const float* w  = (const float*)d_in[1]; // fp32 (1,2,3)
    const float* cb = (const float*)d_in[2]; // fp32 (1,)
    float* out = (float*)d_out;              // fp32 (512,1024)
    float* ws  = (float*)d_ws;               // 512*31*1024 fp32 merged rows

    hipLaunchKernelGGL(merge_tree_kernel, dim3(BATCH), dim3(BDIM), 0, stream,
                       x, w, cb, out, ws);
}